// Round 1
// baseline (871.244 us; speedup 1.0000x reference)
//
#include <hip/hip_runtime.h>
#include <cstdint>
#include <cstddef>

// ---------------------------------------------------------------------------
// GCN2: h = relu(x@W0+b0); 6x { agg = scatter_sum(w*h[src] -> dst);
//        z = 0.9*agg + 0.1*x0; h = relu(0.94593*z + 0.05407*(z@Wc)) };
//        out = h@W1 + b1
// Round 0: correct fp32 implementation. CSR built on-device per call
// (histogram + single-block scan + bucket), pull-style aggregation (no
// atomics in hot loop), tiled fused GEMMs on the vector ALU.
// ---------------------------------------------------------------------------

#define NN 50000
#define EE 800000

constexpr float ALPHA   = 0.1f;
constexpr float BETA_C  = 0.05406722127027574f;   // log(0.5/9 + 1)

constexpr int BM = 64;
constexpr int BK = 16;

// ---------------- CSR build ----------------

__global__ void k_hist(const int* __restrict__ dst, int* __restrict__ deg, int E) {
    int i = blockIdx.x * blockDim.x + threadIdx.x;
    if (i < E) atomicAdd(&deg[dst[i]], 1);
}

// single-block exclusive scan of deg[0..N) -> offs[0..N], also copies to cursor
__global__ __launch_bounds__(1024) void k_scan(const int* __restrict__ deg,
                                               int* __restrict__ offs,
                                               int* __restrict__ cursor, int N) {
    __shared__ int sums[1024];
    const int t = threadIdx.x;
    const int chunk = (N + 1023) / 1024;
    int b = t * chunk; if (b > N) b = N;
    int e = b + chunk; if (e > N) e = N;
    int s = 0;
    for (int i = b; i < e; ++i) s += deg[i];
    sums[t] = s;
    __syncthreads();
    // Hillis-Steele inclusive scan over the 1024 partial sums
    for (int off = 1; off < 1024; off <<= 1) {
        int u = (t >= off) ? sums[t - off] : 0;
        __syncthreads();
        sums[t] += u;
        __syncthreads();
    }
    int run = sums[t] - s;           // exclusive base for this chunk
    for (int i = b; i < e; ++i) {
        int d = deg[i];
        offs[i]   = run;
        cursor[i] = run;
        run += d;
    }
    if (t == 1023) offs[N] = sums[1023];
}

__global__ void k_bucket(const int* __restrict__ src, const int* __restrict__ dst,
                         const float* __restrict__ w, int* __restrict__ cursor,
                         int* __restrict__ ssrc, float* __restrict__ swt, int E) {
    int i = blockIdx.x * blockDim.x + threadIdx.x;
    if (i < E) {
        int d = dst[i];
        int p = atomicAdd(&cursor[d], 1);
        ssrc[p] = src[i];
        swt[p]  = w[i];
    }
}

// ---------------- aggregation (pull, no atomics) ----------------
// one block per node, 128 threads = one feature per thread
__global__ __launch_bounds__(128) void k_aggregate(const int* __restrict__ offs,
                                                   const int* __restrict__ ssrc,
                                                   const float* __restrict__ swt,
                                                   const float* __restrict__ h,
                                                   float* __restrict__ agg, int N) {
    const int n = blockIdx.x;
    const int t = threadIdx.x;
    const int beg = offs[n], end = offs[n + 1];
    float acc = 0.f;
    int e = beg;
    for (; e + 3 < end; e += 4) {
        int   s0 = ssrc[e],   s1 = ssrc[e + 1], s2 = ssrc[e + 2], s3 = ssrc[e + 3];
        float w0 = swt[e],    w1 = swt[e + 1],  w2 = swt[e + 2],  w3 = swt[e + 3];
        acc += w0 * h[(size_t)s0 * 128 + t];
        acc += w1 * h[(size_t)s1 * 128 + t];
        acc += w2 * h[(size_t)s2 * 128 + t];
        acc += w3 * h[(size_t)s3 * 128 + t];
    }
    for (; e < end; ++e) acc += swt[e] * h[(size_t)ssrc[e] * 128 + t];
    agg[(size_t)n * 128 + t] = acc;
}

// ---------------- fused tiled GEMM ----------------
// C[M,BN] = f(A[M,128] @ W[128,BN])
// MODE 0: C = relu(A@W + bias)                       (first layer)
// MODE 1: z = 0.9*A + 0.1*A2 (fused in A-staging);
//         C = relu((1-beta)*z + beta*(z@W))          (GCN2 conv)
// MODE 2: C = A@W + bias                             (final layer)
template <int BN, int MODE>
__global__ __launch_bounds__(256) void k_gemm(const float* __restrict__ A,
                                              const float* __restrict__ A2,
                                              const float* __restrict__ W,
                                              const float* __restrict__ bias,
                                              float* __restrict__ C, int M) {
    __shared__ float sA[BK][BM + 4];   // [k][m], +4 pad: bank-conflict-free & 16B rows
    __shared__ float sB[BK][BN];
    constexpr int CN = BN / 32;        // cols per thread (4 or 2)
    const int tid = threadIdx.x;
    const int tx = tid & 31, ty = tid >> 5;
    const int row0 = blockIdx.x * BM;

    float acc[8][CN];
#pragma unroll
    for (int i = 0; i < 8; ++i)
#pragma unroll
        for (int j = 0; j < CN; ++j) acc[i][j] = 0.f;

    for (int k0 = 0; k0 < 128; k0 += BK) {
        // ---- stage A tile (64 rows x 16 k), fused z-transform for MODE 1
        {
            const int r  = tid >> 2;          // 0..63
            const int c4 = (tid & 3) * 4;     // 0,4,8,12
            const int grow = row0 + r;
            float4 v = make_float4(0.f, 0.f, 0.f, 0.f);
            if (grow < M) {
                v = *(const float4*)(A + (size_t)grow * 128 + k0 + c4);
                if (MODE == 1) {
                    float4 u = *(const float4*)(A2 + (size_t)grow * 128 + k0 + c4);
                    v.x = (1.f - ALPHA) * v.x + ALPHA * u.x;
                    v.y = (1.f - ALPHA) * v.y + ALPHA * u.y;
                    v.z = (1.f - ALPHA) * v.z + ALPHA * u.z;
                    v.w = (1.f - ALPHA) * v.w + ALPHA * u.w;
                }
            }
            sA[c4 + 0][r] = v.x;
            sA[c4 + 1][r] = v.y;
            sA[c4 + 2][r] = v.z;
            sA[c4 + 3][r] = v.w;
        }
        // ---- stage B tile (16 k x BN)
#pragma unroll
        for (int p = 0; p < BN / 64; ++p) {
            int idx = tid + p * 256;              // one float4 each
            int k   = idx / (BN / 4);
            int c4  = (idx - k * (BN / 4)) * 4;
            *(float4*)&sB[k][c4] = *(const float4*)(W + (size_t)(k0 + k) * BN + c4);
        }
        __syncthreads();
        // ---- inner product
#pragma unroll
        for (int k = 0; k < BK; ++k) {
            float a[8], b[CN];
#pragma unroll
            for (int i = 0; i < 8; ++i) a[i] = sA[k][ty * 8 + i];
#pragma unroll
            for (int j = 0; j < CN; ++j) b[j] = sB[k][tx * CN + j];
#pragma unroll
            for (int i = 0; i < 8; ++i)
#pragma unroll
                for (int j = 0; j < CN; ++j) acc[i][j] += a[i] * b[j];
        }
        __syncthreads();
    }

    // ---- epilogue
    const int col0 = tx * CN;
#pragma unroll
    for (int i = 0; i < 8; ++i) {
        const int row = row0 + ty * 8 + i;
        if (row < M) {
            float* Crow = C + (size_t)row * BN + col0;
            if (MODE == 0) {
#pragma unroll
                for (int j = 0; j < CN; ++j) {
                    float v = acc[i][j] + bias[col0 + j];
                    Crow[j] = v > 0.f ? v : 0.f;
                }
            } else if (MODE == 1) {
                const float* ag = A  + (size_t)row * 128 + col0;
                const float* x0 = A2 + (size_t)row * 128 + col0;
#pragma unroll
                for (int j = 0; j < CN; ++j) {
                    float z = (1.f - ALPHA) * ag[j] + ALPHA * x0[j];
                    float v = (1.f - BETA_C) * z + BETA_C * acc[i][j];
                    Crow[j] = v > 0.f ? v : 0.f;
                }
            } else {
#pragma unroll
                for (int j = 0; j < CN; ++j) Crow[j] = acc[i][j] + bias[col0 + j];
            }
        }
    }
}

// ---------------------------------------------------------------------------

extern "C" void kernel_launch(void* const* d_in, const int* in_sizes, int n_in,
                              void* d_out, int out_size, void* d_ws, size_t ws_size,
                              hipStream_t stream) {
    const float* x    = (const float*)d_in[0];
    const int*   esrc = (const int*)d_in[1];
    const int*   edst = (const int*)d_in[2];
    const float* ew   = (const float*)d_in[3];
    const float* W0   = (const float*)d_in[4];
    const float* b0   = (const float*)d_in[5];
    const float* W1   = (const float*)d_in[6];
    const float* b1   = (const float*)d_in[7];
    const float* cw   = (const float*)d_in[8];
    float* out = (float*)d_out;

    const int N = NN, E = EE;

    // workspace layout (all fully rewritten every call)
    float* x0b  = (float*)d_ws;                 // [N,128]  h after layer 0 == x0
    float* hb   = x0b + (size_t)N * 128;        // [N,128]  current h
    float* aggb = hb  + (size_t)N * 128;        // [N,128]  aggregation buffer
    int*   deg  = (int*)(aggb + (size_t)N * 128);
    int*   offs = deg  + N;                     // N+1
    int*   cur  = offs + N + 1;                 // N
    int*   ssrc = cur  + N;                     // E  (edge src sorted by dst)
    float* swt  = (float*)(ssrc + E);           // E  (edge weight sorted by dst)

    // ---- CSR build (once per call, reused by all 6 convs)
    hipMemsetAsync(deg, 0, (size_t)N * sizeof(int), stream);
    k_hist<<<(E + 255) / 256, 256, 0, stream>>>(edst, deg, E);
    k_scan<<<1, 1024, 0, stream>>>(deg, offs, cur, N);
    k_bucket<<<(E + 255) / 256, 256, 0, stream>>>(esrc, edst, ew, cur, ssrc, swt, E);

    const int gx = (N + BM - 1) / BM;

    // ---- layer 0: x0 = h = relu(x@W0 + b0)
    k_gemm<128, 0><<<gx, 256, 0, stream>>>(x, nullptr, W0, b0, x0b, N);

    // ---- 6 GCN2 convs
    const float* curh = x0b;
    for (int i = 0; i < 6; ++i) {
        k_aggregate<<<N, 128, 0, stream>>>(offs, ssrc, swt, curh, aggb, N);
        k_gemm<128, 1><<<gx, 256, 0, stream>>>(aggb, x0b, cw + (size_t)i * 128 * 128,
                                               nullptr, hb, N);
        curh = hb;
    }

    // ---- final: out = h@W1 + b1
    k_gemm<64, 2><<<gx, 256, 0, stream>>>(hb, nullptr, W1, b1, out, N);
}

// Round 2
// 769.731 us; speedup vs baseline: 1.1319x; 1.1319x over previous
//
#include <hip/hip_runtime.h>
#include <cstdint>
#include <cstddef>

// ---------------------------------------------------------------------------
// GCN2: h = relu(x@W0+b0); 6x { agg = scatter_sum(w*h[src] -> dst);
//        z = 0.9*agg + 0.1*x0; h = relu(0.94593*z + 0.05407*(z@Wc)) };
//        out = h@W1 + b1
// R0: correct fp32 baseline, 871 us. k_scan (single-block) was 110 us.
// R1: two-level multi-block scan (196 blocks) -> scan cost ~10 us.
// ---------------------------------------------------------------------------

#define NN 50000
#define EE 800000

constexpr float ALPHA   = 0.1f;
constexpr float BETA_C  = 0.05406722127027574f;   // log(0.5/9 + 1)

constexpr int BM = 64;
constexpr int BK = 16;

constexpr int SCAN_B = 256;
constexpr int NB = (NN + SCAN_B - 1) / SCAN_B;    // 196 scan blocks

// ---------------- CSR build ----------------

__global__ void k_hist(const int* __restrict__ dst, int* __restrict__ deg, int E) {
    int i = blockIdx.x * blockDim.x + threadIdx.x;
    if (i < E) atomicAdd(&deg[dst[i]], 1);
}

// level 1: per-block sum of 256 deg entries
__global__ __launch_bounds__(SCAN_B) void k_bsum(const int* __restrict__ deg,
                                                 int* __restrict__ bsum, int N) {
    int i = blockIdx.x * SCAN_B + threadIdx.x;
    int v = (i < N) ? deg[i] : 0;
#pragma unroll
    for (int o = 32; o > 0; o >>= 1) v += __shfl_down(v, o);   // 64-lane wave
    __shared__ int ws[SCAN_B / 64];
    if ((threadIdx.x & 63) == 0) ws[threadIdx.x >> 6] = v;
    __syncthreads();
    if (threadIdx.x == 0) bsum[blockIdx.x] = ws[0] + ws[1] + ws[2] + ws[3];
}

// level 2: single tiny block scans the 196 block sums (exclusive)
__global__ __launch_bounds__(SCAN_B) void k_bscan(const int* __restrict__ bsum,
                                                  int* __restrict__ bbase, int nb) {
    __shared__ int s[SCAN_B];
    const int t = threadIdx.x;
    int v = (t < nb) ? bsum[t] : 0;
    s[t] = v;
    __syncthreads();
#pragma unroll
    for (int o = 1; o < SCAN_B; o <<= 1) {
        int u = (t >= o) ? s[t - o] : 0;
        __syncthreads();
        s[t] += u;
        __syncthreads();
    }
    if (t < nb) bbase[t] = s[t] - v;     // exclusive base per block
}

// level 3: in-block exclusive scan + block base -> offs/cursor
__global__ __launch_bounds__(SCAN_B) void k_scan3(const int* __restrict__ deg,
                                                  const int* __restrict__ bbase,
                                                  int* __restrict__ offs,
                                                  int* __restrict__ cursor, int N) {
    __shared__ int s[SCAN_B];
    const int t = threadIdx.x;
    const int i = blockIdx.x * SCAN_B + t;
    int v = (i < N) ? deg[i] : 0;
    s[t] = v;
    __syncthreads();
#pragma unroll
    for (int o = 1; o < SCAN_B; o <<= 1) {
        int u = (t >= o) ? s[t - o] : 0;
        __syncthreads();
        s[t] += u;
        __syncthreads();
    }
    int ex = bbase[blockIdx.x] + s[t] - v;
    if (i < N) {
        offs[i]   = ex;
        cursor[i] = ex;
        if (i == N - 1) offs[N] = ex + v;   // total edge count
    }
}

__global__ void k_bucket(const int* __restrict__ src, const int* __restrict__ dst,
                         const float* __restrict__ w, int* __restrict__ cursor,
                         int* __restrict__ ssrc, float* __restrict__ swt, int E) {
    int i = blockIdx.x * blockDim.x + threadIdx.x;
    if (i < E) {
        int d = dst[i];
        int p = atomicAdd(&cursor[d], 1);
        ssrc[p] = src[i];
        swt[p]  = w[i];
    }
}

// ---------------- aggregation (pull, no atomics) ----------------
// one block per node, 128 threads = one feature per thread
__global__ __launch_bounds__(128) void k_aggregate(const int* __restrict__ offs,
                                                   const int* __restrict__ ssrc,
                                                   const float* __restrict__ swt,
                                                   const float* __restrict__ h,
                                                   float* __restrict__ agg, int N) {
    const int n = blockIdx.x;
    const int t = threadIdx.x;
    const int beg = offs[n], end = offs[n + 1];
    float acc = 0.f;
    int e = beg;
    for (; e + 3 < end; e += 4) {
        int   s0 = ssrc[e],   s1 = ssrc[e + 1], s2 = ssrc[e + 2], s3 = ssrc[e + 3];
        float w0 = swt[e],    w1 = swt[e + 1],  w2 = swt[e + 2],  w3 = swt[e + 3];
        acc += w0 * h[(size_t)s0 * 128 + t];
        acc += w1 * h[(size_t)s1 * 128 + t];
        acc += w2 * h[(size_t)s2 * 128 + t];
        acc += w3 * h[(size_t)s3 * 128 + t];
    }
    for (; e < end; ++e) acc += swt[e] * h[(size_t)ssrc[e] * 128 + t];
    agg[(size_t)n * 128 + t] = acc;
}

// ---------------- fused tiled GEMM ----------------
// C[M,BN] = f(A[M,128] @ W[128,BN])
// MODE 0: C = relu(A@W + bias)                       (first layer)
// MODE 1: z = 0.9*A + 0.1*A2 (fused in A-staging);
//         C = relu((1-beta)*z + beta*(z@W))          (GCN2 conv)
// MODE 2: C = A@W + bias                             (final layer)
template <int BN, int MODE>
__global__ __launch_bounds__(256) void k_gemm(const float* __restrict__ A,
                                              const float* __restrict__ A2,
                                              const float* __restrict__ W,
                                              const float* __restrict__ bias,
                                              float* __restrict__ C, int M) {
    __shared__ float sA[BK][BM + 4];   // [k][m], +4 pad: bank-conflict-free & 16B rows
    __shared__ float sB[BK][BN];
    constexpr int CN = BN / 32;        // cols per thread (4 or 2)
    const int tid = threadIdx.x;
    const int tx = tid & 31, ty = tid >> 5;
    const int row0 = blockIdx.x * BM;

    float acc[8][CN];
#pragma unroll
    for (int i = 0; i < 8; ++i)
#pragma unroll
        for (int j = 0; j < CN; ++j) acc[i][j] = 0.f;

    for (int k0 = 0; k0 < 128; k0 += BK) {
        // ---- stage A tile (64 rows x 16 k), fused z-transform for MODE 1
        {
            const int r  = tid >> 2;          // 0..63
            const int c4 = (tid & 3) * 4;     // 0,4,8,12
            const int grow = row0 + r;
            float4 v = make_float4(0.f, 0.f, 0.f, 0.f);
            if (grow < M) {
                v = *(const float4*)(A + (size_t)grow * 128 + k0 + c4);
                if (MODE == 1) {
                    float4 u = *(const float4*)(A2 + (size_t)grow * 128 + k0 + c4);
                    v.x = (1.f - ALPHA) * v.x + ALPHA * u.x;
                    v.y = (1.f - ALPHA) * v.y + ALPHA * u.y;
                    v.z = (1.f - ALPHA) * v.z + ALPHA * u.z;
                    v.w = (1.f - ALPHA) * v.w + ALPHA * u.w;
                }
            }
            sA[c4 + 0][r] = v.x;
            sA[c4 + 1][r] = v.y;
            sA[c4 + 2][r] = v.z;
            sA[c4 + 3][r] = v.w;
        }
        // ---- stage B tile (16 k x BN)
#pragma unroll
        for (int p = 0; p < BN / 64; ++p) {
            int idx = tid + p * 256;              // one float4 each
            int k   = idx / (BN / 4);
            int c4  = (idx - k * (BN / 4)) * 4;
            *(float4*)&sB[k][c4] = *(const float4*)(W + (size_t)(k0 + k) * BN + c4);
        }
        __syncthreads();
        // ---- inner product
#pragma unroll
        for (int k = 0; k < BK; ++k) {
            float a[8], b[CN];
#pragma unroll
            for (int i = 0; i < 8; ++i) a[i] = sA[k][ty * 8 + i];
#pragma unroll
            for (int j = 0; j < CN; ++j) b[j] = sB[k][tx * CN + j];
#pragma unroll
            for (int i = 0; i < 8; ++i)
#pragma unroll
                for (int j = 0; j < CN; ++j) acc[i][j] += a[i] * b[j];
        }
        __syncthreads();
    }

    // ---- epilogue
    const int col0 = tx * CN;
#pragma unroll
    for (int i = 0; i < 8; ++i) {
        const int row = row0 + ty * 8 + i;
        if (row < M) {
            float* Crow = C + (size_t)row * BN + col0;
            if (MODE == 0) {
#pragma unroll
                for (int j = 0; j < CN; ++j) {
                    float v = acc[i][j] + bias[col0 + j];
                    Crow[j] = v > 0.f ? v : 0.f;
                }
            } else if (MODE == 1) {
                const float* ag = A  + (size_t)row * 128 + col0;
                const float* x0 = A2 + (size_t)row * 128 + col0;
#pragma unroll
                for (int j = 0; j < CN; ++j) {
                    float z = (1.f - ALPHA) * ag[j] + ALPHA * x0[j];
                    float v = (1.f - BETA_C) * z + BETA_C * acc[i][j];
                    Crow[j] = v > 0.f ? v : 0.f;
                }
            } else {
#pragma unroll
                for (int j = 0; j < CN; ++j) Crow[j] = acc[i][j] + bias[col0 + j];
            }
        }
    }
}

// ---------------------------------------------------------------------------

extern "C" void kernel_launch(void* const* d_in, const int* in_sizes, int n_in,
                              void* d_out, int out_size, void* d_ws, size_t ws_size,
                              hipStream_t stream) {
    const float* x    = (const float*)d_in[0];
    const int*   esrc = (const int*)d_in[1];
    const int*   edst = (const int*)d_in[2];
    const float* ew   = (const float*)d_in[3];
    const float* W0   = (const float*)d_in[4];
    const float* b0   = (const float*)d_in[5];
    const float* W1   = (const float*)d_in[6];
    const float* b1   = (const float*)d_in[7];
    const float* cw   = (const float*)d_in[8];
    float* out = (float*)d_out;

    const int N = NN, E = EE;

    // workspace layout (all fully rewritten every call)
    float* x0b  = (float*)d_ws;                 // [N,128]  h after layer 0 == x0
    float* hb   = x0b + (size_t)N * 128;        // [N,128]  current h
    float* aggb = hb  + (size_t)N * 128;        // [N,128]  aggregation buffer
    int*   deg  = (int*)(aggb + (size_t)N * 128);
    int*   offs = deg  + N;                     // N+1
    int*   cur  = offs + N + 1;                 // N
    int*   bsum = cur  + N;                     // NB
    int*   bbase= bsum + NB;                    // NB
    int*   ssrc = bbase + NB;                   // E  (edge src sorted by dst)
    float* swt  = (float*)(ssrc + E);           // E  (edge weight sorted by dst)

    // ---- CSR build (once per call, reused by all 6 convs)
    hipMemsetAsync(deg, 0, (size_t)N * sizeof(int), stream);
    k_hist<<<(E + 255) / 256, 256, 0, stream>>>(edst, deg, E);
    k_bsum<<<NB, SCAN_B, 0, stream>>>(deg, bsum, N);
    k_bscan<<<1, SCAN_B, 0, stream>>>(bsum, bbase, NB);
    k_scan3<<<NB, SCAN_B, 0, stream>>>(deg, bbase, offs, cur, N);
    k_bucket<<<(E + 255) / 256, 256, 0, stream>>>(esrc, edst, ew, cur, ssrc, swt, E);

    const int gx = (N + BM - 1) / BM;

    // ---- layer 0: x0 = h = relu(x@W0 + b0)
    k_gemm<128, 0><<<gx, 256, 0, stream>>>(x, nullptr, W0, b0, x0b, N);

    // ---- 6 GCN2 convs
    const float* curh = x0b;
    for (int i = 0; i < 6; ++i) {
        k_aggregate<<<N, 128, 0, stream>>>(offs, ssrc, swt, curh, aggb, N);
        k_gemm<128, 1><<<gx, 256, 0, stream>>>(aggb, x0b, cw + (size_t)i * 128 * 128,
                                               nullptr, hb, N);
        curh = hb;
    }

    // ---- final: out = h@W1 + b1
    k_gemm<64, 2><<<gx, 256, 0, stream>>>(hb, nullptr, W1, b1, out, N);
}

// Round 3
// 651.537 us; speedup vs baseline: 1.3372x; 1.1814x over previous
//
#include <hip/hip_runtime.h>
#include <cstdint>
#include <cstddef>

// ---------------------------------------------------------------------------
// GCN2: h = relu(x@W0+b0); 6x { agg = scatter_sum(w*h[src] -> dst);
//        z = 0.9*agg + 0.1*x0; h = relu(0.94593*z + 0.05407*(z@Wc)) };
//        out = h@W1 + b1
// R0: fp32 baseline 871us. R1: multi-block scan -> 770us (k_scan 110->~10us).
// R2: (a) k_bucket packs (src,w) into one int2 8B store (WRITE_SIZE ~halves)
//     (b) bf16 storage for x0/h/agg (fp32 accumulate, fp32 weights):
//         gather traffic 410->205 MB/conv; GEMM A/C traffic halves.
// ---------------------------------------------------------------------------

#define NN 50000
#define EE 800000

constexpr float ALPHA   = 0.1f;
constexpr float BETA_C  = 0.05406722127027574f;   // log(0.5/9 + 1)

constexpr int BM = 64;
constexpr int BK = 16;

constexpr int SCAN_B = 256;
constexpr int NB = (NN + SCAN_B - 1) / SCAN_B;    // 196 scan blocks

typedef unsigned short u16;
typedef unsigned int   u32;

// bf16 helpers (storage-only precision; all math fp32)
__device__ __forceinline__ float bf2f(u16 u) {
    union { float f; u32 i; } c; c.i = ((u32)u) << 16; return c.f;
}
__device__ __forceinline__ u16 f2bf(float f) {          // round-to-nearest-even
    union { float f; u32 i; } c; c.f = f;
    u32 r = c.i + 0x7fffu + ((c.i >> 16) & 1u);
    return (u16)(r >> 16);
}

// ---------------- CSR build ----------------

__global__ void k_hist(const int* __restrict__ dst, int* __restrict__ deg, int E) {
    int i = blockIdx.x * blockDim.x + threadIdx.x;
    if (i < E) atomicAdd(&deg[dst[i]], 1);
}

__global__ __launch_bounds__(SCAN_B) void k_bsum(const int* __restrict__ deg,
                                                 int* __restrict__ bsum, int N) {
    int i = blockIdx.x * SCAN_B + threadIdx.x;
    int v = (i < N) ? deg[i] : 0;
#pragma unroll
    for (int o = 32; o > 0; o >>= 1) v += __shfl_down(v, o);   // 64-lane wave
    __shared__ int ws[SCAN_B / 64];
    if ((threadIdx.x & 63) == 0) ws[threadIdx.x >> 6] = v;
    __syncthreads();
    if (threadIdx.x == 0) bsum[blockIdx.x] = ws[0] + ws[1] + ws[2] + ws[3];
}

__global__ __launch_bounds__(SCAN_B) void k_bscan(const int* __restrict__ bsum,
                                                  int* __restrict__ bbase, int nb) {
    __shared__ int s[SCAN_B];
    const int t = threadIdx.x;
    int v = (t < nb) ? bsum[t] : 0;
    s[t] = v;
    __syncthreads();
#pragma unroll
    for (int o = 1; o < SCAN_B; o <<= 1) {
        int u = (t >= o) ? s[t - o] : 0;
        __syncthreads();
        s[t] += u;
        __syncthreads();
    }
    if (t < nb) bbase[t] = s[t] - v;     // exclusive base per block
}

__global__ __launch_bounds__(SCAN_B) void k_scan3(const int* __restrict__ deg,
                                                  const int* __restrict__ bbase,
                                                  int* __restrict__ offs,
                                                  int* __restrict__ cursor, int N) {
    __shared__ int s[SCAN_B];
    const int t = threadIdx.x;
    const int i = blockIdx.x * SCAN_B + t;
    int v = (i < N) ? deg[i] : 0;
    s[t] = v;
    __syncthreads();
#pragma unroll
    for (int o = 1; o < SCAN_B; o <<= 1) {
        int u = (t >= o) ? s[t - o] : 0;
        __syncthreads();
        s[t] += u;
        __syncthreads();
    }
    int ex = bbase[blockIdx.x] + s[t] - v;
    if (i < N) {
        offs[i]   = ex;
        cursor[i] = ex;
        if (i == N - 1) offs[N] = ex + v;
    }
}

// pack (src, weight) -> single 8B store per edge
__global__ void k_bucket(const int* __restrict__ src, const int* __restrict__ dst,
                         const float* __restrict__ w, int* __restrict__ cursor,
                         int2* __restrict__ ep, int E) {
    int i = blockIdx.x * blockDim.x + threadIdx.x;
    if (i < E) {
        int d = dst[i];
        int p = atomicAdd(&cursor[d], 1);
        ep[p] = make_int2(src[i], __float_as_int(w[i]));
    }
}

// ---------------- aggregation (pull, no atomics, bf16 gather) ----------------
// one 64-lane wave per node; lane t owns features {2t, 2t+1} via one 4B load
__global__ __launch_bounds__(256) void k_aggregate(const int* __restrict__ offs,
                                                   const int2* __restrict__ ep,
                                                   const u16* __restrict__ h,
                                                   u16* __restrict__ agg, int N) {
    const int lane = threadIdx.x & 63;
    const int n = blockIdx.x * 4 + (threadIdx.x >> 6);
    if (n >= N) return;
    const int beg = offs[n], end = offs[n + 1];
    float ax = 0.f, ay = 0.f;
    int e = beg;
    for (; e + 3 < end; e += 4) {
        int2 e0 = ep[e], e1 = ep[e + 1], e2 = ep[e + 2], e3 = ep[e + 3];
        u32 v0 = ((const u32*)(h + (size_t)e0.x * 128))[lane];
        u32 v1 = ((const u32*)(h + (size_t)e1.x * 128))[lane];
        u32 v2 = ((const u32*)(h + (size_t)e2.x * 128))[lane];
        u32 v3 = ((const u32*)(h + (size_t)e3.x * 128))[lane];
        float w0 = __int_as_float(e0.y), w1 = __int_as_float(e1.y);
        float w2 = __int_as_float(e2.y), w3 = __int_as_float(e3.y);
        ax += w0 * bf2f((u16)v0);  ay += w0 * bf2f((u16)(v0 >> 16));
        ax += w1 * bf2f((u16)v1);  ay += w1 * bf2f((u16)(v1 >> 16));
        ax += w2 * bf2f((u16)v2);  ay += w2 * bf2f((u16)(v2 >> 16));
        ax += w3 * bf2f((u16)v3);  ay += w3 * bf2f((u16)(v3 >> 16));
    }
    for (; e < end; ++e) {
        int2 ed = ep[e];
        u32 v = ((const u32*)(h + (size_t)ed.x * 128))[lane];
        float w = __int_as_float(ed.y);
        ax += w * bf2f((u16)v);
        ay += w * bf2f((u16)(v >> 16));
    }
    u32 o = (u32)f2bf(ax) | ((u32)f2bf(ay) << 16);
    ((u32*)(agg + (size_t)n * 128))[lane] = o;
}

// ---------------- fused tiled GEMM (fp32 math, bf16 storage) ----------------
// MODE 0: A fp32 [M,128]; C = relu(A@W + bias) -> bf16
// MODE 1: A=agg bf16, A2=x0 bf16; z = 0.9*A+0.1*A2 (fused in staging);
//         C = relu((1-beta)*z + beta*(z@W)) -> bf16
// MODE 2: A bf16 [M,128]; C = A@W + bias -> fp32
template <int BN, int MODE>
__global__ __launch_bounds__(256) void k_gemm(const void* __restrict__ Av,
                                              const u16* __restrict__ A2,
                                              const float* __restrict__ W,
                                              const float* __restrict__ bias,
                                              void* __restrict__ Cv, int M) {
    __shared__ float sA[BK][BM + 4];
    __shared__ float sB[BK][BN];
    constexpr int CN = BN / 32;        // cols per thread (4 or 2)
    const int tid = threadIdx.x;
    const int tx = tid & 31, ty = tid >> 5;
    const int row0 = blockIdx.x * BM;

    float acc[8][CN];
#pragma unroll
    for (int i = 0; i < 8; ++i)
#pragma unroll
        for (int j = 0; j < CN; ++j) acc[i][j] = 0.f;

    for (int k0 = 0; k0 < 128; k0 += BK) {
        // ---- stage A tile (64 rows x 16 k)
        {
            const int r  = tid >> 2;          // 0..63
            const int c4 = (tid & 3) * 4;     // 0,4,8,12
            const int grow = row0 + r;
            float v0 = 0.f, v1 = 0.f, v2 = 0.f, v3 = 0.f;
            if (grow < M) {
                if (MODE == 0) {
                    float4 v = *(const float4*)((const float*)Av + (size_t)grow * 128 + k0 + c4);
                    v0 = v.x; v1 = v.y; v2 = v.z; v3 = v.w;
                } else {
                    ushort4 u = *(const ushort4*)((const u16*)Av + (size_t)grow * 128 + k0 + c4);
                    v0 = bf2f(u.x); v1 = bf2f(u.y); v2 = bf2f(u.z); v3 = bf2f(u.w);
                    if (MODE == 1) {
                        ushort4 q = *(const ushort4*)(A2 + (size_t)grow * 128 + k0 + c4);
                        v0 = (1.f - ALPHA) * v0 + ALPHA * bf2f(q.x);
                        v1 = (1.f - ALPHA) * v1 + ALPHA * bf2f(q.y);
                        v2 = (1.f - ALPHA) * v2 + ALPHA * bf2f(q.z);
                        v3 = (1.f - ALPHA) * v3 + ALPHA * bf2f(q.w);
                    }
                }
            }
            sA[c4 + 0][r] = v0;
            sA[c4 + 1][r] = v1;
            sA[c4 + 2][r] = v2;
            sA[c4 + 3][r] = v3;
        }
        // ---- stage B tile (16 k x BN), fp32 weights
#pragma unroll
        for (int p = 0; p < BN / 64; ++p) {
            int idx = tid + p * 256;
            int k   = idx / (BN / 4);
            int c4  = (idx - k * (BN / 4)) * 4;
            *(float4*)&sB[k][c4] = *(const float4*)(W + (size_t)(k0 + k) * BN + c4);
        }
        __syncthreads();
        // ---- inner product (fp32 VALU FMA)
#pragma unroll
        for (int k = 0; k < BK; ++k) {
            float a[8], b[CN];
#pragma unroll
            for (int i = 0; i < 8; ++i) a[i] = sA[k][ty * 8 + i];
#pragma unroll
            for (int j = 0; j < CN; ++j) b[j] = sB[k][tx * CN + j];
#pragma unroll
            for (int i = 0; i < 8; ++i)
#pragma unroll
                for (int j = 0; j < CN; ++j) acc[i][j] += a[i] * b[j];
        }
        __syncthreads();
    }

    // ---- epilogue
    const int col0 = tx * CN;
#pragma unroll
    for (int i = 0; i < 8; ++i) {
        const int row = row0 + ty * 8 + i;
        if (row < M) {
            if (MODE == 0) {
                ushort4 o;
                float c0 = acc[i][0] + bias[col0 + 0];
                float c1 = acc[i][1] + bias[col0 + 1];
                float c2 = acc[i][2] + bias[col0 + 2];
                float c3 = acc[i][3] + bias[col0 + 3];
                o.x = f2bf(c0 > 0.f ? c0 : 0.f);
                o.y = f2bf(c1 > 0.f ? c1 : 0.f);
                o.z = f2bf(c2 > 0.f ? c2 : 0.f);
                o.w = f2bf(c3 > 0.f ? c3 : 0.f);
                *(ushort4*)((u16*)Cv + (size_t)row * 128 + col0) = o;
            } else if (MODE == 1) {
                ushort4 ag = *(const ushort4*)((const u16*)Av + (size_t)row * 128 + col0);
                ushort4 x0 = *(const ushort4*)(A2 + (size_t)row * 128 + col0);
                ushort4 o;
                float z, v;
                z = (1.f - ALPHA) * bf2f(ag.x) + ALPHA * bf2f(x0.x);
                v = (1.f - BETA_C) * z + BETA_C * acc[i][0];
                o.x = f2bf(v > 0.f ? v : 0.f);
                z = (1.f - ALPHA) * bf2f(ag.y) + ALPHA * bf2f(x0.y);
                v = (1.f - BETA_C) * z + BETA_C * acc[i][1];
                o.y = f2bf(v > 0.f ? v : 0.f);
                z = (1.f - ALPHA) * bf2f(ag.z) + ALPHA * bf2f(x0.z);
                v = (1.f - BETA_C) * z + BETA_C * acc[i][2];
                o.z = f2bf(v > 0.f ? v : 0.f);
                z = (1.f - ALPHA) * bf2f(ag.w) + ALPHA * bf2f(x0.w);
                v = (1.f - BETA_C) * z + BETA_C * acc[i][3];
                o.w = f2bf(v > 0.f ? v : 0.f);
                *(ushort4*)((u16*)Cv + (size_t)row * 128 + col0) = o;
            } else {
                float2 o;
                o.x = acc[i][0] + bias[col0 + 0];
                o.y = acc[i][1] + bias[col0 + 1];
                *(float2*)((float*)Cv + (size_t)row * BN + col0) = o;
            }
        }
    }
}

// ---------------------------------------------------------------------------

extern "C" void kernel_launch(void* const* d_in, const int* in_sizes, int n_in,
                              void* d_out, int out_size, void* d_ws, size_t ws_size,
                              hipStream_t stream) {
    const float* x    = (const float*)d_in[0];
    const int*   esrc = (const int*)d_in[1];
    const int*   edst = (const int*)d_in[2];
    const float* ew   = (const float*)d_in[3];
    const float* W0   = (const float*)d_in[4];
    const float* b0   = (const float*)d_in[5];
    const float* W1   = (const float*)d_in[6];
    const float* b1   = (const float*)d_in[7];
    const float* cw   = (const float*)d_in[8];
    float* out = (float*)d_out;

    const int N = NN, E = EE;

    // workspace layout (epack first -> 8B alignment; all rewritten every call)
    int2* epack = (int2*)d_ws;                      // E      (src, weight bits)
    u16*  x0b   = (u16*)(epack + E);                // [N,128] bf16 x0
    u16*  hb    = x0b + (size_t)N * 128;            // [N,128] bf16 h
    u16*  aggb  = hb  + (size_t)N * 128;            // [N,128] bf16 agg
    int*  deg   = (int*)(aggb + (size_t)N * 128);
    int*  offs  = deg  + N;                         // N+1
    int*  cur   = offs + N + 1;                     // N
    int*  bsum  = cur  + N;                         // NB
    int*  bbase = bsum + NB;                        // NB

    // ---- CSR build (once per call, reused by all 6 convs)
    hipMemsetAsync(deg, 0, (size_t)N * sizeof(int), stream);
    k_hist<<<(E + 255) / 256, 256, 0, stream>>>(edst, deg, E);
    k_bsum<<<NB, SCAN_B, 0, stream>>>(deg, bsum, N);
    k_bscan<<<1, SCAN_B, 0, stream>>>(bsum, bbase, NB);
    k_scan3<<<NB, SCAN_B, 0, stream>>>(deg, bbase, offs, cur, N);
    k_bucket<<<(E + 255) / 256, 256, 0, stream>>>(esrc, edst, ew, cur, epack, E);

    const int gx = (N + BM - 1) / BM;

    // ---- layer 0: x0 = relu(x@W0 + b0)  (fp32 in, bf16 out)
    k_gemm<128, 0><<<gx, 256, 0, stream>>>(x, nullptr, W0, b0, x0b, N);

    // ---- 6 GCN2 convs
    const u16* curh = x0b;
    for (int i = 0; i < 6; ++i) {
        k_aggregate<<<(N + 3) / 4, 256, 0, stream>>>(offs, epack, curh, aggb, N);
        k_gemm<128, 1><<<gx, 256, 0, stream>>>(aggb, x0b, cw + (size_t)i * 128 * 128,
                                               nullptr, hb, N);
        curh = hb;
    }

    // ---- final: out = h@W1 + b1  (bf16 in, fp32 out)
    k_gemm<64, 2><<<gx, 256, 0, stream>>>(hb, nullptr, W1, b1, out, N);
}

// Round 4
// 592.490 us; speedup vs baseline: 1.4705x; 1.0997x over previous
//
#include <hip/hip_runtime.h>
#include <cstdint>
#include <cstddef>

// ---------------------------------------------------------------------------
// GCN2: h = relu(x@W0+b0); 6x { agg = scatter_sum(w*h[src] -> dst);
//        z = 0.9*agg + 0.1*x0; h = relu(0.94593*z + 0.05407*(z@Wc)) };
//        out = h@W1 + b1
// R0 871us fp32 baseline. R1 multi-block scan -> 770. R2 bf16 storage +
// packed bucket -> 652. R3: MFMA GEMMs (16x16x32 bf16) with the GCN2 update
// folded into the weight:  h = relu(z @ ((1-b)I + bW))  (prep kernel builds
// transposed bf16 Wfold once per call); aggregate unrolled x8.
// ---------------------------------------------------------------------------

#define NN 50000
#define EE 800000

constexpr float ALPHA   = 0.1f;
constexpr float BETA_C  = 0.05406722127027574f;   // log(0.5/9 + 1)

constexpr int SCAN_B = 256;
constexpr int NB = (NN + SCAN_B - 1) / SCAN_B;    // 196 scan blocks

typedef unsigned short u16;
typedef unsigned int   u32;
typedef __attribute__((ext_vector_type(8))) short short8;   // 8 bf16 (MFMA A/B)
typedef __attribute__((ext_vector_type(4))) float f32x4;    // MFMA C/D

__device__ __forceinline__ float bf2f(u16 u) {
    union { float f; u32 i; } c; c.i = ((u32)u) << 16; return c.f;
}
__device__ __forceinline__ u16 f2bf(float f) {          // round-to-nearest-even
    union { float f; u32 i; } c; c.f = f;
    u32 r = c.i + 0x7fffu + ((c.i >> 16) & 1u);
    return (u16)(r >> 16);
}

// ---------------- weight prep: transpose + fold, fp32 -> bf16 ----------------
// w0t[n][k] = bf16(W0[k][n])                              (128x128)
// wft[l][n][k] = bf16( beta*cw[l][k][n] + (k==n)*(1-beta) ) (6 x 128x128)
// w1t[n][k] = bf16(W1[k][n])                              (64x128)
__global__ void k_prepw(const float* __restrict__ W0, const float* __restrict__ cw,
                        const float* __restrict__ W1, u16* __restrict__ w0t,
                        u16* __restrict__ wft, u16* __restrict__ w1t) {
    int i = blockIdx.x * blockDim.x + threadIdx.x;
    if (i < 128 * 128) {
        int n = i >> 7, k = i & 127;
        w0t[i] = f2bf(W0[k * 128 + n]);
    } else if (i < 128 * 128 + 6 * 128 * 128) {
        int r = i - 128 * 128;
        int l = r >> 14; int t = r & 16383;
        int n = t >> 7, k = t & 127;
        float v = BETA_C * cw[l * 16384 + k * 128 + n] + ((k == n) ? (1.f - BETA_C) : 0.f);
        wft[r] = f2bf(v);
    } else if (i < 128 * 128 + 6 * 128 * 128 + 64 * 128) {
        int r = i - (128 * 128 + 6 * 128 * 128);
        int n = r >> 7, k = r & 127;
        w1t[r] = f2bf(W1[k * 64 + n]);
    }
}

// ---------------- CSR build ----------------

__global__ void k_hist(const int* __restrict__ dst, int* __restrict__ deg, int E) {
    int i = blockIdx.x * blockDim.x + threadIdx.x;
    if (i < E) atomicAdd(&deg[dst[i]], 1);
}

__global__ __launch_bounds__(SCAN_B) void k_bsum(const int* __restrict__ deg,
                                                 int* __restrict__ bsum, int N) {
    int i = blockIdx.x * SCAN_B + threadIdx.x;
    int v = (i < N) ? deg[i] : 0;
#pragma unroll
    for (int o = 32; o > 0; o >>= 1) v += __shfl_down(v, o);
    __shared__ int ws[SCAN_B / 64];
    if ((threadIdx.x & 63) == 0) ws[threadIdx.x >> 6] = v;
    __syncthreads();
    if (threadIdx.x == 0) bsum[blockIdx.x] = ws[0] + ws[1] + ws[2] + ws[3];
}

__global__ __launch_bounds__(SCAN_B) void k_bscan(const int* __restrict__ bsum,
                                                  int* __restrict__ bbase, int nb) {
    __shared__ int s[SCAN_B];
    const int t = threadIdx.x;
    int v = (t < nb) ? bsum[t] : 0;
    s[t] = v;
    __syncthreads();
#pragma unroll
    for (int o = 1; o < SCAN_B; o <<= 1) {
        int u = (t >= o) ? s[t - o] : 0;
        __syncthreads();
        s[t] += u;
        __syncthreads();
    }
    if (t < nb) bbase[t] = s[t] - v;
}

__global__ __launch_bounds__(SCAN_B) void k_scan3(const int* __restrict__ deg,
                                                  const int* __restrict__ bbase,
                                                  int* __restrict__ offs,
                                                  int* __restrict__ cursor, int N) {
    __shared__ int s[SCAN_B];
    const int t = threadIdx.x;
    const int i = blockIdx.x * SCAN_B + t;
    int v = (i < N) ? deg[i] : 0;
    s[t] = v;
    __syncthreads();
#pragma unroll
    for (int o = 1; o < SCAN_B; o <<= 1) {
        int u = (t >= o) ? s[t - o] : 0;
        __syncthreads();
        s[t] += u;
        __syncthreads();
    }
    int ex = bbase[blockIdx.x] + s[t] - v;
    if (i < N) {
        offs[i]   = ex;
        cursor[i] = ex;
        if (i == N - 1) offs[N] = ex + v;
    }
}

__global__ void k_bucket(const int* __restrict__ src, const int* __restrict__ dst,
                         const float* __restrict__ w, int* __restrict__ cursor,
                         int2* __restrict__ ep, int E) {
    int i = blockIdx.x * blockDim.x + threadIdx.x;
    if (i < E) {
        int d = dst[i];
        int p = atomicAdd(&cursor[d], 1);
        ep[p] = make_int2(src[i], __float_as_int(w[i]));
    }
}

// ---------------- aggregation (pull, no atomics, bf16 gather) ----------------
// one 64-lane wave per node; lane t owns features {2t, 2t+1}; 8 gathers in flight
__global__ __launch_bounds__(256) void k_aggregate(const int* __restrict__ offs,
                                                   const int2* __restrict__ ep,
                                                   const u16* __restrict__ h,
                                                   u16* __restrict__ agg, int N) {
    const int lane = threadIdx.x & 63;
    const int n = blockIdx.x * 4 + (threadIdx.x >> 6);
    if (n >= N) return;
    const int beg = offs[n], end = offs[n + 1];
    float ax = 0.f, ay = 0.f;
    int e = beg;
    for (; e + 7 < end; e += 8) {
        int2 ed[8];
        u32  v[8];
#pragma unroll
        for (int j = 0; j < 8; ++j) ed[j] = ep[e + j];
#pragma unroll
        for (int j = 0; j < 8; ++j)
            v[j] = ((const u32*)(h + (size_t)ed[j].x * 128))[lane];
#pragma unroll
        for (int j = 0; j < 8; ++j) {
            float w = __int_as_float(ed[j].y);
            ax += w * bf2f((u16)v[j]);
            ay += w * bf2f((u16)(v[j] >> 16));
        }
    }
    for (; e < end; ++e) {
        int2 ed = ep[e];
        u32 v = ((const u32*)(h + (size_t)ed.x * 128))[lane];
        float w = __int_as_float(ed.y);
        ax += w * bf2f((u16)v);
        ay += w * bf2f((u16)(v >> 16));
    }
    u32 o = (u32)f2bf(ax) | ((u32)f2bf(ay) << 16);
    ((u32*)(agg + (size_t)n * 128))[lane] = o;
}

// ---------------- MFMA GEMM ----------------
// D = A_op * B_op with A_op = Wt (feature-major), B_op = node fragments, so
// lane's 4 acc regs = 4 consecutive output features of one node (8B store).
// MODE 0: Av = x fp32 [M,128]; C = relu(x@W + bias) -> bf16
// MODE 1: Av = agg bf16, A2 = x0 bf16; zfrag = 0.9*agg+0.1*x0;
//         C = relu(z @ Wfold) -> bf16   (no bias; fold has the identity)
// MODE 2: Av = h bf16; C = h@W + bias -> fp32 [M,64]
// NT = number of 16-feature tiles (8 -> 128 cols, 4 -> 64 cols)
template <int NT, int MODE>
__global__ __launch_bounds__(256) void k_gemm_mfma(const void* __restrict__ Av,
                                                   const u16* __restrict__ A2,
                                                   const u16* __restrict__ Wt,
                                                   const float* __restrict__ bias,
                                                   void* __restrict__ Cv, int M) {
    const int lane = threadIdx.x & 63;
    const int wave = threadIdx.x >> 6;
    const int q = lane >> 4;          // quad 0..3
    const int m16 = lane & 15;        // node within 16-tile / feature within A-op
    const int node = blockIdx.x * 64 + wave * 16 + m16;
    const int nload = node < M ? node : M - 1;

    // ---- stage node fragments zf[s], s = k-step (k = s*32 + q*8 + j)
    short8 zf[4];
    if (MODE == 0) {
        const float* xp = (const float*)Av + (size_t)nload * 128 + q * 8;
#pragma unroll
        for (int s = 0; s < 4; ++s) {
            float4 u0 = *(const float4*)(xp + s * 32);
            float4 u1 = *(const float4*)(xp + s * 32 + 4);
            short8 z;
            z[0] = (short)f2bf(u0.x); z[1] = (short)f2bf(u0.y);
            z[2] = (short)f2bf(u0.z); z[3] = (short)f2bf(u0.w);
            z[4] = (short)f2bf(u1.x); z[5] = (short)f2bf(u1.y);
            z[6] = (short)f2bf(u1.z); z[7] = (short)f2bf(u1.w);
            zf[s] = z;
        }
    } else if (MODE == 1) {
        const u16* ap = (const u16*)Av + (size_t)nload * 128 + q * 8;
        const u16* xp = A2 + (size_t)nload * 128 + q * 8;
#pragma unroll
        for (int s = 0; s < 4; ++s) {
            union { uint4 v; u16 u[8]; } a, b;
            a.v = *(const uint4*)(ap + s * 32);
            b.v = *(const uint4*)(xp + s * 32);
            short8 z;
#pragma unroll
            for (int j = 0; j < 8; ++j) {
                float f = (1.f - ALPHA) * bf2f(a.u[j]) + ALPHA * bf2f(b.u[j]);
                z[j] = (short)f2bf(f);
            }
            zf[s] = z;
        }
    } else {
        const u16* ap = (const u16*)Av + (size_t)nload * 128 + q * 8;
#pragma unroll
        for (int s = 0; s < 4; ++s)
            zf[s] = *(const short8*)(ap + s * 32);
    }

    // ---- MFMA: for each 16-feature tile, K=128 in 4 steps
    f32x4 acc[NT];
#pragma unroll
    for (int c = 0; c < NT; ++c) {
        f32x4 a = {0.f, 0.f, 0.f, 0.f};
        const u16* wp = Wt + (size_t)(c * 16 + m16) * 128 + q * 8;
#pragma unroll
        for (int s = 0; s < 4; ++s) {
            short8 wf = *(const short8*)(wp + s * 32);
            a = __builtin_amdgcn_mfma_f32_16x16x32_bf16(wf, zf[s], a, 0, 0, 0);
        }
        acc[c] = a;
    }

    // ---- epilogue: lane holds features n = c*16 + q*4 + r of `node`
    if (node < M) {
#pragma unroll
        for (int c = 0; c < NT; ++c) {
            const int n0 = c * 16 + q * 4;
            if (MODE == 2) {
                float4 bv = *(const float4*)(bias + n0);
                float4 o;
                o.x = acc[c][0] + bv.x; o.y = acc[c][1] + bv.y;
                o.z = acc[c][2] + bv.z; o.w = acc[c][3] + bv.w;
                *(float4*)((float*)Cv + (size_t)node * (NT * 16) + n0) = o;
            } else {
                float v0 = acc[c][0], v1 = acc[c][1], v2 = acc[c][2], v3 = acc[c][3];
                if (MODE == 0) {
                    float4 bv = *(const float4*)(bias + n0);
                    v0 += bv.x; v1 += bv.y; v2 += bv.z; v3 += bv.w;
                }
                v0 = v0 > 0.f ? v0 : 0.f;
                v1 = v1 > 0.f ? v1 : 0.f;
                v2 = v2 > 0.f ? v2 : 0.f;
                v3 = v3 > 0.f ? v3 : 0.f;
                ushort4 o;
                o.x = f2bf(v0); o.y = f2bf(v1); o.z = f2bf(v2); o.w = f2bf(v3);
                *(ushort4*)((u16*)Cv + (size_t)node * 128 + n0) = o;
            }
        }
    }
}

// ---------------------------------------------------------------------------

extern "C" void kernel_launch(void* const* d_in, const int* in_sizes, int n_in,
                              void* d_out, int out_size, void* d_ws, size_t ws_size,
                              hipStream_t stream) {
    const float* x    = (const float*)d_in[0];
    const int*   esrc = (const int*)d_in[1];
    const int*   edst = (const int*)d_in[2];
    const float* ew   = (const float*)d_in[3];
    const float* W0   = (const float*)d_in[4];
    const float* b0   = (const float*)d_in[5];
    const float* W1   = (const float*)d_in[6];
    const float* b1   = (const float*)d_in[7];
    const float* cw   = (const float*)d_in[8];
    float* out = (float*)d_out;

    const int N = NN, E = EE;

    // workspace layout (all rewritten every call)
    int2* epack = (int2*)d_ws;                      // E
    u16*  x0b   = (u16*)(epack + E);                // [N,128] bf16
    u16*  hb    = x0b + (size_t)N * 128;            // [N,128] bf16
    u16*  aggb  = hb  + (size_t)N * 128;            // [N,128] bf16
    u16*  w0t   = aggb + (size_t)N * 128;           // 128*128
    u16*  wft   = w0t + 128 * 128;                  // 6*128*128
    u16*  w1t   = wft + 6 * 128 * 128;              // 64*128
    int*  deg   = (int*)(w1t + 64 * 128);
    int*  offs  = deg  + N;                         // N+1
    int*  cur   = offs + N + 1;                     // N
    int*  bsum  = cur  + N;                         // NB
    int*  bbase = bsum + NB;                        // NB

    // ---- weight prep (independent of CSR chain)
    {
        int tot = 128 * 128 + 6 * 128 * 128 + 64 * 128;
        k_prepw<<<(tot + 255) / 256, 256, 0, stream>>>(W0, cw, W1, w0t, wft, w1t);
    }

    // ---- CSR build (once per call, reused by all 6 convs)
    hipMemsetAsync(deg, 0, (size_t)N * sizeof(int), stream);
    k_hist<<<(E + 255) / 256, 256, 0, stream>>>(edst, deg, E);
    k_bsum<<<NB, SCAN_B, 0, stream>>>(deg, bsum, N);
    k_bscan<<<1, SCAN_B, 0, stream>>>(bsum, bbase, NB);
    k_scan3<<<NB, SCAN_B, 0, stream>>>(deg, bbase, offs, cur, N);
    k_bucket<<<(E + 255) / 256, 256, 0, stream>>>(esrc, edst, ew, cur, epack, E);

    const int gx = (N + 63) / 64;   // 782 blocks of 4 waves (16 nodes/wave)

    // ---- layer 0: x0 = relu(x@W0 + b0)
    k_gemm_mfma<8, 0><<<gx, 256, 0, stream>>>(x, nullptr, w0t, b0, x0b, N);

    // ---- 6 GCN2 convs: agg -> h = relu((0.9*agg+0.1*x0) @ Wfold)
    const u16* curh = x0b;
    for (int i = 0; i < 6; ++i) {
        k_aggregate<<<(N + 3) / 4, 256, 0, stream>>>(offs, epack, curh, aggb, N);
        k_gemm_mfma<8, 1><<<gx, 256, 0, stream>>>(aggb, x0b, wft + (size_t)i * 16384,
                                                  nullptr, hb, N);
        curh = hb;
    }

    // ---- final: out = h@W1 + b1
    k_gemm_mfma<4, 2><<<gx, 256, 0, stream>>>(hb, nullptr, w1t, b1, out, N);
}